// Round 9
// baseline (333.241 us; speedup 1.0000x reference)
//
#include <hip/hip_runtime.h>

// ---------------------------------------------------------------------------
// HypothesisDecoder — Round 9: PT=32 @ 1024 threads, 32x32x16 MFMA,
// L4 fused into conv3 epilogue (reg-level dot + LDS atomics), MLP interp.
// r8 falsified occupancy theory (12->21 waves: dur flat). New levers:
// halve unique-A L2 traffic + block count (PT=32), halve MFMA instr count
// and per-col B traffic (32x32 tiles), remove L4 phase + 2 barriers + 160KB
// LDS/block (fusion). acc = 2 x f32x16 = 32 regs -> 16 waves fit 128-reg cap.
// ---------------------------------------------------------------------------
#define GG 96
#define NB 2
#define RESV 0.04f

constexpr int NG  = NB * GG * GG * GG;  // dense voxel grid (1,769,472 cells)
constexpr int PT  = 32;                 // points per block
constexpr int NCOLS = PT * 8;           // 256 point-cols
constexpr int XC  = NCOLS + 2;          // 258 LDS u-cols
constexpr int CS  = 136;                // LDS stride in halves (272B = 68 dw)

typedef _Float16 f16x8 __attribute__((ext_vector_type(8)));
typedef _Float16 f16x4 __attribute__((ext_vector_type(4)));
typedef float    f32x4 __attribute__((ext_vector_type(4)));
typedef float    f32x16 __attribute__((ext_vector_type(16)));

// ---------------------------------------------------------------------------
__global__ void k_scatter(const int* __restrict__ coords, const int* __restrict__ sbatch,
                          int n, unsigned* __restrict__ grid, int* __restrict__ minc) {
    __shared__ int lmin[6];
    int tid = threadIdx.x;
    if (tid < 6) lmin[tid] = 0x7fffffff;
    __syncthreads();
    int i = blockIdx.x * 256 + tid;
    if (i < n) {
        int cx = coords[3*i], cy = coords[3*i+1], cz = coords[3*i+2];
        int b = sbatch[i];
        // stable-argsort + leftmost searchsorted == keep smallest original index
        atomicMin(&grid[((b*GG + cx)*GG + cy)*GG + cz], (unsigned)i);
        atomicMin(&lmin[b*3+0], cx);
        atomicMin(&lmin[b*3+1], cy);
        atomicMin(&lmin[b*3+2], cz);
    }
    __syncthreads();
    if (tid < 6) atomicMin(&minc[tid], lmin[tid]);
}

// ---------------------------------------------------------------------------
// Weights -> fp16 fragments for mfma_f32_32x32x16_f16, BN scale folded in.
// Fragment idx: (((mt*KS + ks)*64 + lane)*8 + j); element:
//   row = mt*32 + (lane&31), k = ks*16 + (lane>>5)*8 + j, tap=k/CIN, c=k%CIN
__global__ void k_wconv(const float* __restrict__ w1, const float* __restrict__ w2,
                        const float* __restrict__ w3,
                        const float* __restrict__ g1, const float* __restrict__ b1,
                        const float* __restrict__ m1, const float* __restrict__ v1,
                        const float* __restrict__ g2, const float* __restrict__ b2,
                        const float* __restrict__ m2, const float* __restrict__ v2,
                        const float* __restrict__ g3, const float* __restrict__ b3,
                        const float* __restrict__ m3, const float* __restrict__ v3,
                        _Float16* __restrict__ o1, _Float16* __restrict__ o2,
                        _Float16* __restrict__ o3, float* __restrict__ tvec) {
    int e = blockIdx.x * 256 + threadIdx.x;
    if (e < 24576) {                              // layer 1: KS16=12, mt 0..3
        int j = e & 7, lane = (e >> 3) & 63, t2 = e >> 9;   // t2 in [0,48)
        int mt = t2 / 12, ks = t2 % 12;
        int row = mt * 32 + (lane & 31);
        int k = ks * 16 + ((lane >> 5) << 3) + j;
        int tap = k >> 6, c = k & 63;
        float s = g1[row] / sqrtf(v1[row] + 1e-5f);
        o1[e] = (_Float16)(w1[(row * 64 + c) * 3 + tap] * s);
    } else if (e < 122880) {                      // layers 2/3: KS16=24
        int u = e - 24576;
        int layer = u / 49152;
        u %= 49152;
        int j = u & 7, lane = (u >> 3) & 63, t2 = u >> 9;   // t2 in [0,96)
        int mt = t2 / 24, ks = t2 % 24;
        int row = mt * 32 + (lane & 31);
        int k = ks * 16 + ((lane >> 5) << 3) + j;
        int tap = k >> 7, c = k & 127;
        const float* w = layer ? w3 : w2;
        const float* g = layer ? g3 : g2;
        const float* v = layer ? v3 : v2;
        float s = g[row] / sqrtf(v[row] + 1e-5f);
        (layer ? o3 : o2)[u] = (_Float16)(w[(row * 128 + c) * 3 + tap] * s);
    } else if (e < 123264) {                      // tvec: 3 x 128
        int i = e - 122880;
        int layer = i >> 7, ch = i & 127;
        const float* g = layer == 0 ? g1 : (layer == 1 ? g2 : g3);
        const float* b = layer == 0 ? b1 : (layer == 1 ? b2 : b3);
        const float* m = layer == 0 ? m1 : (layer == 1 ? m2 : m3);
        const float* v = layer == 0 ? v1 : (layer == 1 ? v2 : v3);
        float s = g[ch] / sqrtf(v[ch] + 1e-5f);
        tvec[i] = b[ch] - m[ch] * s;
    }
}

// ---------------------------------------------------------------------------
// k_interp: one thread per query. MLP-friendly: all 8 grid probes issued
// with clamped addresses before any dependent use, then hit accumulation.
__global__ __launch_bounds__(256, 4) void k_interp(
    const float* __restrict__ pdh, const int* __restrict__ pts_batch,
    const float* __restrict__ sfeats, const unsigned* __restrict__ grid,
    const int* __restrict__ minc, _Float16* __restrict__ X, int NQ, int n_sp)
{
    int q = blockIdx.x * 256 + threadIdx.x;
    if (q >= NQ) return;
    int pg = q / 7;
    int b = pts_batch[pg];
    const float* pd = pdh + (size_t)q * 3;
    float qx = (pd[0] - (float)minc[b*3+0] * RESV) / RESV;
    float qy = (pd[1] - (float)minc[b*3+1] * RESV) / RESV;
    float qz = (pd[2] - (float)minc[b*3+2] * RESV) / RESV;
    float flx = floorf(qx), fly = floorf(qy), flz = floorf(qz);
    float fx = qx - flx, fy = qy - fly, fz = qz - flz;
    int ix0 = (int)flx, iy0 = (int)fly, iz0 = (int)flz;

    unsigned si[8];
    float    wt[8];
    bool     ok[8];
#pragma unroll
    for (int c8 = 0; c8 < 8; ++c8) {
        int dx = c8 >> 2, dy = (c8 >> 1) & 1, dz = c8 & 1;
        int cx = ix0 + dx, cy = iy0 + dy, cz = iz0 + dz;
        bool inb = ((unsigned)cx < GG) & ((unsigned)cy < GG) & ((unsigned)cz < GG);
        int cxc = min(max(cx, 0), GG - 1);
        int cyc = min(max(cy, 0), GG - 1);
        int czc = min(max(cz, 0), GG - 1);
        si[c8] = grid[((b * GG + cxc) * GG + cyc) * GG + czc];   // issued early
        wt[c8] = (dx ? fx : 1.f - fx) * (dy ? fy : 1.f - fy) * (dz ? fz : 1.f - fz);
        ok[c8] = inb;
    }
    float acc[32];
#pragma unroll
    for (int k2 = 0; k2 < 32; ++k2) acc[k2] = 0.f;
#pragma unroll
    for (int c8 = 0; c8 < 8; ++c8) {
        if (ok[c8] && si[c8] < (unsigned)n_sp) {
            float w = wt[c8];
            const float4* fp = (const float4*)(sfeats + (size_t)si[c8] * 32);
#pragma unroll
            for (int v4 = 0; v4 < 8; ++v4) {
                float4 f = fp[v4];
                acc[v4*4+0] += w * f.x; acc[v4*4+1] += w * f.y;
                acc[v4*4+2] += w * f.z; acc[v4*4+3] += w * f.w;
            }
        }
    }
    _Float16* xp = X + (size_t)q * 32;
#pragma unroll
    for (int c8 = 0; c8 < 4; ++c8) {
        f16x8 hv;
#pragma unroll
        for (int k2 = 0; k2 < 8; ++k2) hv[k2] = (_Float16)acc[c8*8 + k2];
        *(f16x8*)(xp + c8*8) = hv;
    }
}

// ---------------------------------------------------------------------------
// In-place conv layer, 32x32x16 MFMA, 16 waves: wave w -> mp=w&1 (which 64
// out-ch), colq=w>>1 (32 cols). acc = 2 x f32x16 (mi = ch-tile) = 32 regs.
// Per k16-step: 2 A global loads + 1 B ds_read_b128 -> 2 MFMA.
// FUSE=true (conv3): no hX writes; layer-4 dot from f32 regs + shfl + LDS
// atomics into lg[] (softmax is shift-invariant so bias4 drops out).
// D layout (HW-verified m74/m101): col=lane&31, row=(r&3)+8*(r>>2)+4*(lane>>5)
template<int CIN, int KS, bool FUSE>
__device__ __forceinline__ void conv32(
    _Float16* hx, const _Float16* __restrict__ wg, const float* tvl,
    const float* w4s, float* lg, int tid)
{
    const int wave = tid >> 6;
    const int lane = tid & 63;
    const int half = lane >> 5;
    const int c32  = lane & 31;
    const int mp   = wave & 1;
    const int n    = (wave >> 1) * 32 + c32;      // point-col of this lane

    f32x16 acc0 = {};
    f32x16 acc1 = {};

#pragma unroll
    for (int ks = 0; ks < KS; ++ks) {
        f16x8 A0 = *(const f16x8*)(wg + ((((mp * 2 + 0) * KS + ks) * 64 + lane) << 3));
        f16x8 A1 = *(const f16x8*)(wg + ((((mp * 2 + 1) * KS + ks) * 64 + lane) << 3));
        const int k0  = ks * 16 + half * 8;
        const int tap = k0 / CIN;                 // CIN 64/128 -> shift
        const int c   = k0 & (CIN - 1);
        f16x8 Bf = *(const f16x8*)(hx + (n + tap) * CS + c);
        acc0 = __builtin_amdgcn_mfma_f32_32x32x16_f16(A0, Bf, acc0, 0, 0, 0);
        acc1 = __builtin_amdgcn_mfma_f32_32x32x16_f16(A1, Bf, acc1, 0, 0, 0);
    }

    const bool alive = (n & 7) != 7;              // u = n+1 dead iff n%8==7

    if constexpr (!FUSE) {
        __syncthreads();                          // reads done before in-place writes
        if (alive) {
            _Float16* dst = hx + (n + 1) * CS;
#pragma unroll
            for (int mi = 0; mi < 2; ++mi) {
                const f32x16& a = mi ? acc1 : acc0;
                const int base = (mp * 2 + mi) * 32;
#pragma unroll
                for (int g4 = 0; g4 < 4; ++g4) {
                    const int chb = base + 8 * g4 + 4 * half;
                    f32x4 tb = *(const f32x4*)(tvl + chb);
                    f16x4 o;
#pragma unroll
                    for (int bb = 0; bb < 4; ++bb)
                        o[bb] = (_Float16)fmaxf(a[4*g4+bb] + tb[bb], 0.f);
                    *(f16x4*)(dst + chb) = o;
                }
            }
        }
    } else {
        float d0 = 0.f, d1 = 0.f, d2 = 0.f;
        if (alive) {
#pragma unroll
            for (int mi = 0; mi < 2; ++mi) {
                const f32x16& a = mi ? acc1 : acc0;
                const int base = (mp * 2 + mi) * 32;
#pragma unroll
                for (int g4 = 0; g4 < 4; ++g4) {
                    const int chb = base + 8 * g4 + 4 * half;
                    f32x4 tb = *(const f32x4*)(tvl + chb);
                    f32x4 wv0 = *(const f32x4*)(w4s + chb);          // tap 0
                    f32x4 wv1 = *(const f32x4*)(w4s + 128 + chb);    // tap 1
                    f32x4 wv2 = *(const f32x4*)(w4s + 256 + chb);    // tap 2
#pragma unroll
                    for (int bb = 0; bb < 4; ++bb) {
                        float y = fmaxf(a[4*g4+bb] + tb[bb], 0.f);
                        d0 += y * wv0[bb];
                        d1 += y * wv1[bb];
                        d2 += y * wv2[bb];
                    }
                }
            }
        }
        d0 += __shfl_xor(d0, 32);                 // combine the two ch-halves
        d1 += __shfl_xor(d1, 32);
        d2 += __shfl_xor(d2, 32);
        if (half == 0 && alive) {                 // h col u=n+1 -> lg[n+1-t]
            if (n > 0) atomicAdd(&lg[n - 1], d2);
            atomicAdd(&lg[n], d1);
            if (n < NCOLS - 1) atomicAdd(&lg[n + 1], d0);
        }
    }
}

// ---------------------------------------------------------------------------
__global__ __launch_bounds__(1024) void k_mainX(
    const _Float16* __restrict__ X, const float* __restrict__ ptsfeat,
    const _Float16* __restrict__ w16_1, const _Float16* __restrict__ w16_2,
    const _Float16* __restrict__ w16_3, const float* __restrict__ tvec,
    const float* __restrict__ w4, float* __restrict__ out, int N)
{
    __shared__ __align__(16) _Float16 hX[XC * CS];   // 70.2 KB, in-place
    __shared__ __align__(16) float    tv[384];
    __shared__ __align__(16) float    w4s[384];      // [tap][ch] f32
    __shared__ float lg[NCOLS];

    const int tid = threadIdx.x;
    const int p0  = blockIdx.x * PT;
    const int ncol = min(PT * 7, N * 7 - p0 * 7);

    if (tid < 384) {
        tv[tid]  = tvec[tid];
        w4s[tid] = w4[(tid & 127) * 3 + (tid >> 7)];
    }
    if (tid < NCOLS) lg[tid] = 0.f;
    // zero the 34 dead/pad u-cols (u = 0,8,...,256 and 257): 34*68 dwords
    for (int idx = tid; idx < 34 * 68; idx += 1024) {
        int cidx = idx / 68, off = idx % 68;
        int u = (cidx < 33) ? cidx * 8 : 257;
        ((int*)hX)[u * 68 + off] = 0;
    }

    // stage X (fp16, 224 q x 4 parts) + ptsfeat (fp32->fp16): 1792 tasks
    for (int t = tid; t < 1792; t += 1024) {
        int task = t >> 2, part = t & 3;
        int col  = task % 224;
        if (col < ncol) {
            int pl = col / 7, j = col - pl * 7;
            int u  = pl * 8 + 1 + j;
            size_t q = (size_t)p0 * 7 + col;
            if (task < 224) {
                f16x8 hv = *(const f16x8*)(X + q * 32 + part * 8);
                *(f16x8*)(hX + u * CS + part * 8) = hv;
            } else {
                const float4* pf = (const float4*)(ptsfeat + q * 32 + part * 8);
                float4 f0 = pf[0], f1 = pf[1];
                f16x8 pv;
                pv[0] = (_Float16)f0.x; pv[1] = (_Float16)f0.y;
                pv[2] = (_Float16)f0.z; pv[3] = (_Float16)f0.w;
                pv[4] = (_Float16)f1.x; pv[5] = (_Float16)f1.y;
                pv[6] = (_Float16)f1.z; pv[7] = (_Float16)f1.w;
                *(f16x8*)(hX + u * CS + 32 + part * 8) = pv;
            }
        }
    }
    __syncthreads();

    conv32<64,  12, false>(hX, w16_1, tv,       nullptr, nullptr, tid);
    __syncthreads();
    conv32<128, 24, false>(hX, w16_2, tv + 128, nullptr, nullptr, tid);
    __syncthreads();
    conv32<128, 24, true >(hX, w16_3, tv + 256, w4s, lg, tid);   // fused L4
    __syncthreads();

    // softmax over 7 hypotheses (bias4 dropped: softmax shift-invariant)
    if (tid < PT) {
        int pg = p0 + tid;
        if (pg < N) {
            float l0[7];
            float mx = -1e30f;
#pragma unroll
            for (int j = 0; j < 7; ++j) { l0[j] = lg[tid * 8 + j]; mx = fmaxf(mx, l0[j]); }
            float s = 0.f;
#pragma unroll
            for (int j = 0; j < 7; ++j) { l0[j] = __expf(l0[j] - mx); s += l0[j]; }
            float inv = 1.f / s;
#pragma unroll
            for (int j = 0; j < 7; ++j) out[(size_t)pg * 7 + j] = l0[j] * inv;
        }
    }
}

// ---------------------------------------------------------------------------
extern "C" void kernel_launch(void* const* d_in, const int* in_sizes, int n_in,
                              void* d_out, int out_size, void* d_ws, size_t ws_size,
                              hipStream_t stream) {
    const int*   sparse_coords = (const int*)d_in[1];
    const int*   sparse_batch  = (const int*)d_in[2];
    const float* sparse_feats  = (const float*)d_in[3];
    const float* pdh           = (const float*)d_in[4];
    const float* ptsfeat       = (const float*)d_in[5];
    const int*   pts_batch     = (const int*)d_in[6];
    const float* w1 = (const float*)d_in[7];
    const float* g1 = (const float*)d_in[8],  *b1 = (const float*)d_in[9];
    const float* m1 = (const float*)d_in[10], *v1 = (const float*)d_in[11];
    const float* w2 = (const float*)d_in[12];
    const float* g2 = (const float*)d_in[13], *b2 = (const float*)d_in[14];
    const float* m2 = (const float*)d_in[15], *v2 = (const float*)d_in[16];
    const float* w3 = (const float*)d_in[17];
    const float* g3 = (const float*)d_in[18], *b3 = (const float*)d_in[19];
    const float* m3 = (const float*)d_in[20], *v3 = (const float*)d_in[21];
    const float* w4 = (const float*)d_in[22];

    const int n_sp = in_sizes[2];
    const int N    = in_sizes[6];
    const int NQ   = N * 7;

    // workspace: [grid NG u32][minc 6][pad][w16_1|w16_2|w16_3][tvec][X]
    unsigned* grid = (unsigned*)d_ws;
    int*      minc = (int*)(grid + NG);
    _Float16* w16_1 = (_Float16*)((char*)d_ws + (size_t)(NG + 6) * 4 + 8);
    _Float16* w16_2 = w16_1 + 128 * 192;
    _Float16* w16_3 = w16_2 + 128 * 384;
    float*    tvec  = (float*)(w16_3 + 128 * 384);
    _Float16* X     = (_Float16*)(tvec + 384 + 4);    // 16B aligned

    // grid sentinel 0xFFFFFFFF (max unsigned); minc 0x7F7F7F7F (large +int)
    hipMemsetAsync(grid, 0xFF, (size_t)NG * 4, stream);
    hipMemsetAsync(minc, 0x7F, 6 * 4, stream);

    k_scatter<<<(n_sp + 255) / 256, 256, 0, stream>>>(sparse_coords, sparse_batch,
                                                      n_sp, grid, minc);
    k_wconv<<<482, 256, 0, stream>>>(w1, w2, w3,
                                     g1, b1, m1, v1, g2, b2, m2, v2, g3, b3, m3, v3,
                                     w16_1, w16_2, w16_3, tvec);
    k_interp<<<(NQ + 255) / 256, 256, 0, stream>>>(
        pdh, pts_batch, sparse_feats, grid, minc, X, NQ, n_sp);
    k_mainX<<<(N + PT - 1) / PT, 1024, 0, stream>>>(
        X, ptsfeat, w16_1, w16_2, w16_3, tvec, w4, (float*)d_out, N);
}